// Round 4
// baseline (686.391 us; speedup 1.0000x reference)
//
#include <hip/hip_runtime.h>
#include <math.h>

#define IN_DIM 256
#define HD 128
#define OUT_DIM 40
#define S2_STRIDE 64
#define NB_CS 1024  // colsum blocks in fuse1
#define NXCD 8
#define NCHUNK 8    // edge-list chunks (mapped to XCDs)
#define NRANGE 32   // dst ranges
#define RMAX 3200   // max dsts per range (N <= 102400)

// physical XCD id (0..7), verified on gfx950 via s_getreg(HW_REG_XCC_ID)
__device__ __forceinline__ int xcc_id() {
    int x;
    asm volatile("s_getreg_b32 %0, hwreg(HW_REG_XCC_ID)" : "=s"(x));
    return x & (NXCD - 1);
}

// ---------------- init ----------------
__global__ __launch_bounds__(256) void k_init(float* muacc8) {
    int i = blockIdx.x * 256 + threadIdx.x;
    if (i < NXCD * 256) muacc8[i] = 0.f;
}

// ---------------- fuse1: colsum (float4) + count-sort histogram + wprep ----
// count role: block (r,c) scans edge chunk c, LDS-histograms dsts in range r.
// No global atomics anywhere.
__global__ __launch_bounds__(256) void k_fuse1(const float* __restrict__ x, int N,
                                               float* __restrict__ muacc8,
                                               const int* __restrict__ ei, int E,
                                               unsigned short* __restrict__ cntH,
                                               const float* __restrict__ W0,
                                               const float* __restrict__ W1,
                                               const float* __restrict__ W2,
                                               unsigned long long* W0p,
                                               unsigned long long* W1p,
                                               unsigned long long* W2p,
                                               float* aS0, float* aS1, float* aS2) {
    __shared__ __align__(16) unsigned ldsbuf[RMAX];
    int b = blockIdx.x, tid = threadIdx.x;
    if (b < NB_CS) {                       // ---- colsum ----
        float* lds = (float*)ldsbuf;
        size_t F4 = (size_t)N * (IN_DIM / 4);
        size_t stride = (size_t)NB_CS * 256;
        float a0 = 0.f, a1 = 0.f, a2 = 0.f, a3 = 0.f;
        const float4* x4 = (const float4*)x;
        for (size_t i = (size_t)b * 256 + tid; i < F4; i += stride) {
            float4 v = x4[i];
            a0 += v.x; a1 += v.y; a2 += v.z; a3 += v.w;
        }
        lds[tid] = 0.f;
        __syncthreads();
        int c0 = (tid * 4) & 255;
        atomicAdd(&lds[c0], a0);
        atomicAdd(&lds[c0 + 1], a1);
        atomicAdd(&lds[c0 + 2], a2);
        atomicAdd(&lds[c0 + 3], a3);
        __syncthreads();
        int xc = xcc_id();
        __hip_atomic_fetch_add(&muacc8[xc * 256 + tid], lds[tid],
                               __ATOMIC_RELAXED, __HIP_MEMORY_SCOPE_WORKGROUP);
    } else if (b < NB_CS + NCHUNK * NRANGE) {  // ---- count histogram ----
        int bid2 = b - NB_CS;
        int c = bid2 & (NCHUNK - 1), r = bid2 >> 3;
        for (int i = tid; i < RMAX; i += 256) ldsbuf[i] = 0u;
        __syncthreads();
        int R = (N + NRANGE - 1) / NRANGE;
        int base = r * R;
        int lim = N - base; if (lim > R) lim = R; if (lim < 0) lim = 0;
        int chunk = ((E + NCHUNK - 1) / NCHUNK + 3) & ~3;
        int eBeg = c * chunk, eEnd = E < eBeg + chunk ? E : eBeg + chunk;
        const int* dptr = ei + E;
        int e = eBeg;
        if ((((unsigned)(E + eBeg)) & 3u) == 0) {
            int n4 = (eEnd - eBeg) >> 2;
            const int4* d4 = (const int4*)(dptr + eBeg);
            for (int i = tid; i < n4; i += 256) {
                int4 v = d4[i];
                unsigned r0 = (unsigned)(v.x - base);
                unsigned r1 = (unsigned)(v.y - base);
                unsigned r2 = (unsigned)(v.z - base);
                unsigned r3 = (unsigned)(v.w - base);
                if (r0 < (unsigned)lim) atomicAdd(&ldsbuf[r0], 1u);
                if (r1 < (unsigned)lim) atomicAdd(&ldsbuf[r1], 1u);
                if (r2 < (unsigned)lim) atomicAdd(&ldsbuf[r2], 1u);
                if (r3 < (unsigned)lim) atomicAdd(&ldsbuf[r3], 1u);
            }
            e = eBeg + (n4 << 2);
        }
        for (e += tid; e < eEnd; e += 256) {
            unsigned rel = (unsigned)(dptr[e] - base);
            if (rel < (unsigned)lim) atomicAdd(&ldsbuf[rel], 1u);
        }
        __syncthreads();
        for (int i = tid; i < lim; i += 256)
            cntH[(size_t)c * N + base + i] = (unsigned short)ldsbuf[i];
    } else {                               // ---- wprep ----
        int b2 = b - NB_CS - NCHUNK * NRANGE;
        int lane = tid & 63, w = tid >> 6;
        if (b2 < 32) {                     // W0: [256,128]
            int j = b2 * 4 + w;
            float asum = 0.f;
            unsigned long long words[4];
            #pragma unroll
            for (int q = 0; q < 4; ++q) {
                float v = W0[(size_t)(4 * lane + q) * HD + j];
                asum += fabsf(v);
                words[q] = __ballot(v < 0.f);
            }
            #pragma unroll
            for (int off = 32; off; off >>= 1) asum += __shfl_xor(asum, off);
            if (lane == 0) {
                aS0[j] = 2.f * asum / 256.f;
                #pragma unroll
                for (int q = 0; q < 4; ++q) W0p[j * 4 + q] = words[q];
            }
        } else if (b2 < 64) {              // W1: [128,128]
            int j = (b2 - 32) * 4 + w;
            int fl = lane & 15, kk = lane >> 4;
            float asum = 0.f;
            unsigned long long words[2];
            #pragma unroll
            for (int q = 0; q < 2; ++q) {
                float v = W1[(size_t)(fl * 8 + 4 * q + kk) * HD + j];
                asum += fabsf(v);
                words[q] = __ballot(v < 0.f);
            }
            #pragma unroll
            for (int off = 32; off; off >>= 1) asum += __shfl_xor(asum, off);
            if (lane == 0) {
                aS1[j] = 2.f * asum / 128.f;
                W1p[j * 2 + 0] = words[0];
                W1p[j * 2 + 1] = words[1];
            }
        } else {                           // W2: [128,40]
            int j = (b2 - 64) * 4 + w;
            int fl = lane & 15, kk = lane >> 4;
            if (j < OUT_DIM) {
                float asum = 0.f;
                unsigned long long words[2];
                #pragma unroll
                for (int q = 0; q < 2; ++q) {
                    float v = W2[(size_t)(fl * 8 + 4 * q + kk) * OUT_DIM + j];
                    asum += fabsf(v);
                    words[q] = __ballot(v < 0.f);
                }
                #pragma unroll
                for (int off = 32; off; off >>= 1) asum += __shfl_xor(asum, off);
                if (lane == 0) {
                    aS2[j] = 2.f * asum / 128.f;
                    W2p[j * 2 + 0] = words[0];
                    W2p[j * 2 + 1] = words[1];
                }
            }
        }
    }
}

// ---------------- CSR build (small kernels) ----------------
// k_bp: per-node prefix over the 8 chunk counts -> packed xoffp (u64 of 8 bytes),
// total count (cnt), dinv; per-block sums for CSR scan.
__global__ __launch_bounds__(256) void k_bp(const unsigned short* __restrict__ cntH, int N,
                                            int* bp, unsigned long long* __restrict__ xoffp,
                                            float* __restrict__ dinv, int* __restrict__ cnt) {
    __shared__ int sm[256];
    int i = blockIdx.x * 256 + threadIdx.x;
    int c = 0;
    if (i < N) {
        int run = 0;
        unsigned long long pack = 0;
        #pragma unroll
        for (int h = 0; h < NCHUNK; ++h) {
            unsigned bc = cntH[(size_t)h * N + i];
            pack |= (unsigned long long)(unsigned)run << (8 * h);
            run += (int)bc;
        }
        xoffp[i] = pack;
        c = run;
        cnt[i] = run;
        dinv[i] = (float)(1.0 / sqrt((double)(run + 1)));   // +1 self loop
    }
    sm[threadIdx.x] = c;
    __syncthreads();
    for (int off = 128; off; off >>= 1) {
        if (threadIdx.x < off) sm[threadIdx.x] += sm[threadIdx.x + off];
        __syncthreads();
    }
    if (threadIdx.x == 0) bp[blockIdx.x] = sm[0];
}

__global__ __launch_bounds__(512) void k_scanbp(const int* __restrict__ bp, int NB, int* bps,
                                                const float* __restrict__ muacc8,
                                                float* __restrict__ mu) {
    __shared__ int sm[512];
    int t = threadIdx.x;
    if (t < 256) {                         // finalize column sums
        float s = 0.f;
        #pragma unroll
        for (int xc = 0; xc < NXCD; ++xc) s += muacc8[xc * 256 + t];
        mu[t] = s;
    }
    int v = (t < NB) ? bp[t] : 0;
    sm[t] = v;
    __syncthreads();
    for (int off = 1; off < 512; off <<= 1) {
        int add = (t >= off) ? sm[t - off] : 0;
        __syncthreads();
        sm[t] += add;
        __syncthreads();
    }
    if (t < NB) bps[t] = sm[t] - v;        // exclusive
}

__global__ __launch_bounds__(256) void k_rowptr(const int* __restrict__ cnt,
                                                const int* __restrict__ bps, int N, int E,
                                                int* row_ptr) {
    __shared__ int wsum[4];
    int t = threadIdx.x, lane = t & 63, w = t >> 6;
    int i = blockIdx.x * 256 + t;
    int c = (i < N) ? cnt[i] : 0;
    int v = c;
    #pragma unroll
    for (int off = 1; off < 64; off <<= 1) {
        int n = __shfl_up(v, off);
        if (lane >= off) v += n;
    }
    if (lane == 63) wsum[w] = v;
    __syncthreads();
    int wo = 0;
    for (int k = 0; k < w; ++k) wo += wsum[k];
    int excl = bps[blockIdx.x] + wo + v - c;
    if (i < N) row_ptr[i] = excl;
    if (blockIdx.x == 0 && t == 0) row_ptr[N] = E;
}

// ---------------- fuse2: counting-sort place + layer-0 matmul ----------------
// place role: block (r,c) rescans chunk c, LDS-atomic local ranks for range r,
// writes cs4[rowp[d] + xoff(d,c) + lr] = src. No global atomics.
__global__ __launch_bounds__(256) void k_fuse2(const int* __restrict__ ei, int E,
                                               const int* __restrict__ rowp,
                                               const unsigned long long* __restrict__ xoffp,
                                               int* __restrict__ cs4,
                                               const float* __restrict__ x,
                                               const float* __restrict__ muacc, float inv_n,
                                               const unsigned long long* __restrict__ W0p,
                                               unsigned char* __restrict__ S0, int N) {
    __shared__ __align__(16) unsigned sh32[RMAX];
    int b = blockIdx.x, tid = threadIdx.x;
    if (b < NCHUNK * NRANGE) {             // ---- place ----
        int c = b & (NCHUNK - 1), r = b >> 3;
        for (int i = tid; i < RMAX; i += 256) sh32[i] = 0u;
        __syncthreads();
        int R = (N + NRANGE - 1) / NRANGE;
        int base = r * R;
        int lim = N - base; if (lim > R) lim = R; if (lim < 0) lim = 0;
        int chunk = ((E + NCHUNK - 1) / NCHUNK + 3) & ~3;
        int eBeg = c * chunk, eEnd = E < eBeg + chunk ? E : eBeg + chunk;
        int e = eBeg;
        if (((unsigned)eBeg & 3u) == 0 && (((unsigned)(E + eBeg)) & 3u) == 0) {
            int n4 = (eEnd - eBeg) >> 2;
            const int4* s4p = (const int4*)(ei + eBeg);
            const int4* d4p = (const int4*)(ei + E + eBeg);
            for (int i = tid; i < n4; i += 256) {
                int4 sv = s4p[i];
                int4 dv = d4p[i];
                int ss[4] = {sv.x, sv.y, sv.z, sv.w};
                int dd[4] = {dv.x, dv.y, dv.z, dv.w};
                #pragma unroll
                for (int k = 0; k < 4; ++k) {
                    unsigned rel = (unsigned)(dd[k] - base);
                    if (rel < (unsigned)lim) {
                        unsigned lr = atomicAdd(&sh32[rel], 1u);
                        int pos = rowp[dd[k]] +
                                  (int)((xoffp[dd[k]] >> (8 * c)) & 0xFFu) + (int)lr;
                        cs4[pos] = ss[k];
                    }
                }
            }
            e = eBeg + (n4 << 2);
        }
        for (e += tid; e < eEnd; e += 256) {
            int d = ei[E + e];
            unsigned rel = (unsigned)(d - base);
            if (rel < (unsigned)lim) {
                unsigned lr = atomicAdd(&sh32[rel], 1u);
                int pos = rowp[d] + (int)((xoffp[d] >> (8 * c)) & 0xFFu) + (int)lr;
                cs4[pos] = ei[e];
            }
        }
    } else {                               // ---- x_mm0 ----
        unsigned long long* w0s = (unsigned long long*)sh32;  // stride-9 layout, 576 words
        {
            int i = tid;
            w0s[9 * (i >> 3) + (i & 7)] = W0p[i];
            i = tid + 256;
            w0s[9 * (i >> 3) + (i & 7)] = W0p[i];
        }
        __syncthreads();
        int lane = tid & 63;
        int row = (b - NCHUNK * NRANGE) * 4 + (tid >> 6);
        if (row >= N) return;
        float4 xv = ((const float4*)(x + (size_t)row * IN_DIM))[lane];
        float4 ms = ((const float4*)muacc)[lane];
        unsigned long long xw[4];
        xw[0] = __ballot(xv.x < ms.x * inv_n);
        xw[1] = __ballot(xv.y < ms.y * inv_n);
        xw[2] = __ballot(xv.z < ms.z * inv_n);
        xw[3] = __ballot(xv.w < ms.w * inv_n);
        unsigned int pack = 0;
        #pragma unroll
        for (int t2 = 0; t2 < 2; ++t2) {
            const unsigned long long* wc = &w0s[9 * lane + 4 * t2];
            int dd = __popcll(xw[0] ^ wc[0]) + __popcll(xw[1] ^ wc[1]) +
                     __popcll(xw[2] ^ wc[2]) + __popcll(xw[3] ^ wc[3]);
            int S = IN_DIM - 2 * dd;   // even, [-256,256]
            int s8 = S >> 1;
            if (s8 > 127) s8 = 127;
            pack |= ((unsigned int)(s8 + 128) & 0xffu) << (8 * t2);
        }
        *(unsigned short*)(S0 + (size_t)row * HD + 2 * lane) = (unsigned short)pack;
    }
}

// byte->float unpack + centering: (v>>8k)&0xff maps to v_cvt_f32_ubyteN
__device__ __forceinline__ void acc4s(float n, unsigned v, float* a) {
    a[0] = fmaf(n, (float)(v & 0xffu) - 128.f, a[0]);
    a[1] = fmaf(n, (float)((v >> 8) & 0xffu) - 128.f, a[1]);
    a[2] = fmaf(n, (float)((v >> 16) & 0xffu) - 128.f, a[2]);
    a[3] = fmaf(n, (float)(v >> 24) - 128.f, a[3]);
}

// ---------------- agg + binarize + fused next popcount matmul ----------------
// wave = 1 dst; 4 slots x 16 lanes; lane loads 8B; edges batched 4 deep.
template <int OUTC>
__global__ __launch_bounds__(256) void k_agg_mm(const unsigned char* __restrict__ Sin, // [N][128]
                                                const int* __restrict__ row_ptr,
                                                const int* __restrict__ cs4,
                                                const float* __restrict__ dinv,
                                                const float* __restrict__ alphaS,
                                                const float* __restrict__ bias,
                                                const unsigned long long* __restrict__ Wnp,
                                                unsigned char* __restrict__ Sout, int N) {
    __shared__ unsigned long long wsm[OUTC * 2 + OUTC / 4 + 8];  // stride-9 swizzled
    int tid = threadIdx.x;
    for (int i = tid; i < OUTC * 2; i += 256) wsm[9 * (i >> 3) + (i & 7)] = Wnp[i];
    __syncthreads();
    int lane = tid & 63;
    int d = blockIdx.x * 4 + (tid >> 6);
    if (d >= N) return;
    int sub = lane >> 4;       // edge slot 0..3
    int fl  = lane & 15;       // 8-byte feature group
    float dv = dinv[d];
    float acc[8];
    #pragma unroll
    for (int k = 0; k < 8; ++k) acc[k] = 0.f;
    if (sub == 0) {            // self loop
        float nrm = dv * dv;
        unsigned long long rr = *(const unsigned long long*)(Sin + (size_t)d * HD + fl * 8);
        acc4s(nrm, (unsigned)rr, acc);
        acc4s(nrm, (unsigned)(rr >> 32), acc + 4);
    }
    int e0 = row_ptr[d], e1 = row_ptr[d + 1];
    int e = e0 + sub;
    for (; e + 12 < e1; e += 16) {         // 4 edges in flight
        int s0_ = cs4[e], s1_ = cs4[e + 4], s2_ = cs4[e + 8], s3_ = cs4[e + 12];
        float n0 = dinv[s0_] * dv, n1 = dinv[s1_] * dv;
        float n2 = dinv[s2_] * dv, n3 = dinv[s3_] * dv;
        unsigned long long r0 = *(const unsigned long long*)(Sin + (size_t)s0_ * HD + fl * 8);
        unsigned long long r1 = *(const unsigned long long*)(Sin + (size_t)s1_ * HD + fl * 8);
        unsigned long long r2 = *(const unsigned long long*)(Sin + (size_t)s2_ * HD + fl * 8);
        unsigned long long r3 = *(const unsigned long long*)(Sin + (size_t)s3_ * HD + fl * 8);
        acc4s(n0, (unsigned)r0, acc); acc4s(n0, (unsigned)(r0 >> 32), acc + 4);
        acc4s(n1, (unsigned)r1, acc); acc4s(n1, (unsigned)(r1 >> 32), acc + 4);
        acc4s(n2, (unsigned)r2, acc); acc4s(n2, (unsigned)(r2 >> 32), acc + 4);
        acc4s(n3, (unsigned)r3, acc); acc4s(n3, (unsigned)(r3 >> 32), acc + 4);
    }
    for (; e + 4 < e1; e += 8) {           // 2 edges
        int sa = cs4[e], sb = cs4[e + 4];
        float na = dinv[sa] * dv, nb = dinv[sb] * dv;
        unsigned long long ra = *(const unsigned long long*)(Sin + (size_t)sa * HD + fl * 8);
        unsigned long long rb = *(const unsigned long long*)(Sin + (size_t)sb * HD + fl * 8);
        acc4s(na, (unsigned)ra, acc); acc4s(na, (unsigned)(ra >> 32), acc + 4);
        acc4s(nb, (unsigned)rb, acc); acc4s(nb, (unsigned)(rb >> 32), acc + 4);
    }
    if (e < e1) {                          // tail
        int s = cs4[e];
        float nrm = dinv[s] * dv;
        unsigned long long rr = *(const unsigned long long*)(Sin + (size_t)s * HD + fl * 8);
        acc4s(nrm, (unsigned)rr, acc);
        acc4s(nrm, (unsigned)(rr >> 32), acc + 4);
    }
    // reduce across the 4 slots (allreduce -> every lane has full acc)
    #pragma unroll
    for (int k = 0; k < 8; ++k) {
        acc[k] += __shfl_xor(acc[k], 16);
        acc[k] += __shfl_xor(acc[k], 32);
    }
    // activation sign bits: feature f = fl*8 + k
    unsigned int m8 = 0;
    #pragma unroll
    for (int k = 0; k < 8; ++k) {
        int f = fl * 8 + k;
        float v = alphaS[f] * acc[k] + bias[f];
        if (v < 0.f) m8 |= (1u << k);
    }
    // assemble 128-bit sign vector: word q=k>>2, bit (fl + 16*(k&3))
    unsigned long long x0 = 0, x1 = 0;
    #pragma unroll
    for (int k = 0; k < 4; ++k) {
        unsigned long long bk = __ballot((m8 >> k) & 1u);
        x0 |= (bk & 0xffffULL) << (16 * k);
    }
    #pragma unroll
    for (int k = 4; k < 8; ++k) {
        unsigned long long bk = __ballot((m8 >> k) & 1u);
        x1 |= (bk & 0xffffULL) << (16 * (k - 4));
    }
    if (OUTC == 128) {
        unsigned int pack = 0;
        #pragma unroll
        for (int t2 = 0; t2 < 2; ++t2) {
            int j = 2 * lane + t2;
            int i0 = j * 2;
            const unsigned long long* wc = &wsm[9 * (i0 >> 3) + (i0 & 7)];
            int dd = __popcll(x0 ^ wc[0]) + __popcll(x1 ^ wc[1]);
            int S = HD - 2 * dd;  // even, [-128,128]
            pack |= ((unsigned int)((S >> 1) + 128) & 0xffu) << (8 * t2);
        }
        *(unsigned short*)(Sout + (size_t)d * HD + 2 * lane) = (unsigned short)pack;
    } else {
        int p8 = 128;  // biased zero padding
        if (lane < OUTC) {
            int i0 = lane * 2;
            const unsigned long long* wc = &wsm[9 * (i0 >> 3) + (i0 & 7)];
            int dd = __popcll(x0 ^ wc[0]) + __popcll(x1 ^ wc[1]);
            p8 = ((HD - 2 * dd) >> 1) + 128;
        }
        Sout[(size_t)d * S2_STRIDE + lane] = (unsigned char)p8;
    }
}

// ---------------- final agg + log_softmax ----------------
__global__ __launch_bounds__(256) void k_agg_out(const unsigned char* __restrict__ S2, // [N][64]
                                                 const int* __restrict__ row_ptr,
                                                 const int* __restrict__ cs4,
                                                 const float* __restrict__ dinv,
                                                 const float* __restrict__ alphaS2,
                                                 const float* __restrict__ b2,
                                                 float* __restrict__ out, int N) {
    int tid = threadIdx.x, lane = tid & 63;
    int d = blockIdx.x * 4 + (tid >> 6);
    if (d >= N) return;
    int sub = lane >> 4;
    int fl  = lane & 15;
    float dv = dinv[d];
    float acc[4] = {0.f, 0.f, 0.f, 0.f};
    if (sub == 0) {            // self loop
        float nrm = dv * dv;
        unsigned int r4 = *(const unsigned int*)(S2 + (size_t)d * S2_STRIDE + fl * 4);
        acc4s(nrm, r4, acc);
    }
    int e0 = row_ptr[d], e1 = row_ptr[d + 1];
    int e = e0 + sub;
    for (; e + 12 < e1; e += 16) {         // 4 edges in flight
        int s0_ = cs4[e], s1_ = cs4[e + 4], s2_ = cs4[e + 8], s3_ = cs4[e + 12];
        float n0 = dinv[s0_] * dv, n1 = dinv[s1_] * dv;
        float n2 = dinv[s2_] * dv, n3 = dinv[s3_] * dv;
        unsigned int r0 = *(const unsigned int*)(S2 + (size_t)s0_ * S2_STRIDE + fl * 4);
        unsigned int r1 = *(const unsigned int*)(S2 + (size_t)s1_ * S2_STRIDE + fl * 4);
        unsigned int r2 = *(const unsigned int*)(S2 + (size_t)s2_ * S2_STRIDE + fl * 4);
        unsigned int r3 = *(const unsigned int*)(S2 + (size_t)s3_ * S2_STRIDE + fl * 4);
        acc4s(n0, r0, acc);
        acc4s(n1, r1, acc);
        acc4s(n2, r2, acc);
        acc4s(n3, r3, acc);
    }
    for (; e + 4 < e1; e += 8) {
        int sa = cs4[e], sb = cs4[e + 4];
        float na = dinv[sa] * dv, nb = dinv[sb] * dv;
        unsigned int ra = *(const unsigned int*)(S2 + (size_t)sa * S2_STRIDE + fl * 4);
        unsigned int rb = *(const unsigned int*)(S2 + (size_t)sb * S2_STRIDE + fl * 4);
        acc4s(na, ra, acc);
        acc4s(nb, rb, acc);
    }
    if (e < e1) {
        int s = cs4[e];
        float nrm = dinv[s] * dv;
        unsigned int r4 = *(const unsigned int*)(S2 + (size_t)s * S2_STRIDE + fl * 4);
        acc4s(nrm, r4, acc);
    }
    #pragma unroll
    for (int k = 0; k < 4; ++k) {
        acc[k] += __shfl_xor(acc[k], 16);
        acc[k] += __shfl_xor(acc[k], 32);
    }
    float h[4];
    float mymax = -INFINITY;
    #pragma unroll
    for (int k = 0; k < 4; ++k) {
        int f = fl * 4 + k;
        h[k] = (f < OUT_DIM) ? (alphaS2[f] * acc[k] + b2[f]) : -INFINITY;
        mymax = fmaxf(mymax, h[k]);
    }
    #pragma unroll
    for (int off = 1; off < 16; off <<= 1) mymax = fmaxf(mymax, __shfl_xor(mymax, off));
    float s4 = 0.f;
    #pragma unroll
    for (int k = 0; k < 4; ++k) {
        if (fl * 4 + k < OUT_DIM) s4 += expf(h[k] - mymax);
    }
    #pragma unroll
    for (int off = 1; off < 16; off <<= 1) s4 += __shfl_xor(s4, off);
    float lse = mymax + logf(s4);
    if (sub == 0 && fl < OUT_DIM / 4) {
        float4 o;
        o.x = h[0] - lse; o.y = h[1] - lse; o.z = h[2] - lse; o.w = h[3] - lse;
        *(float4*)(out + (size_t)d * OUT_DIM + fl * 4) = o;
    }
}

// ---------------- launcher ----------------
extern "C" void kernel_launch(void* const* d_in, const int* in_sizes, int n_in,
                              void* d_out, int out_size, void* d_ws, size_t ws_size,
                              hipStream_t stream) {
    const float* x  = (const float*)d_in[0];
    const int*   ei = (const int*)d_in[1];
    const float* W0 = (const float*)d_in[2];
    const float* b0 = (const float*)d_in[3];
    const float* W1 = (const float*)d_in[4];
    const float* b1 = (const float*)d_in[5];
    const float* W2 = (const float*)d_in[6];
    const float* b2 = (const float*)d_in[7];
    float* out = (float*)d_out;

    int N = in_sizes[0] / IN_DIM;
    int E = in_sizes[1] / 2;

    char* ws = (char*)d_ws;
    size_t off = 0;
    auto alloc = [&](size_t bytes) -> void* {
        off = (off + 255) & ~(size_t)255;
        void* p = (void*)(ws + off);
        off += bytes;
        return p;
    };
    float* mu     = (float*)alloc(256 * 4);
    float* muacc8 = (float*)alloc(NXCD * 256 * 4);
    unsigned short* cntH = (unsigned short*)alloc((size_t)NCHUNK * N * 2);
    unsigned long long* xoffp = (unsigned long long*)alloc((size_t)N * 8);
    int*   cnt    = (int*)alloc((size_t)N * 4);
    float* dinv   = (float*)alloc((size_t)N * 4);
    int*   rowp   = (int*)alloc(((size_t)N + 1) * 4);
    int*   bp     = (int*)alloc(512 * 4);
    int*   bps    = (int*)alloc(512 * 4);
    int*   cs4    = (int*)alloc((size_t)E * 4);
    unsigned char* S0 = (unsigned char*)alloc((size_t)N * HD);
    unsigned char* S1 = (unsigned char*)alloc((size_t)N * HD);
    unsigned char* S2 = (unsigned char*)alloc((size_t)N * S2_STRIDE);
    unsigned long long* W0p = (unsigned long long*)alloc(128 * 4 * 8);
    unsigned long long* W1p = (unsigned long long*)alloc(128 * 2 * 8);
    unsigned long long* W2p = (unsigned long long*)alloc(40 * 2 * 8);
    float* aS0 = (float*)alloc(128 * 4);
    float* aS1 = (float*)alloc(128 * 4);
    float* aS2 = (float*)alloc(40 * 4);

    int nb256 = (N + 255) / 256;
    float inv_n = 1.0f / (float)N;

    k_init<<<dim3(8), dim3(256), 0, stream>>>(muacc8);
    k_fuse1<<<dim3(NB_CS + NCHUNK * NRANGE + 74), dim3(256), 0, stream>>>(
        x, N, muacc8, ei, E, cntH, W0, W1, W2, W0p, W1p, W2p, aS0, aS1, aS2);
    k_bp<<<dim3(nb256), dim3(256), 0, stream>>>(cntH, N, bp, xoffp, dinv, cnt);
    k_scanbp<<<dim3(1), dim3(512), 0, stream>>>(bp, nb256, bps, muacc8, mu);
    k_rowptr<<<dim3(nb256), dim3(256), 0, stream>>>(cnt, bps, N, E, rowp);

    int nb4 = (N + 3) / 4;
    k_fuse2<<<dim3(NCHUNK * NRANGE + nb4), dim3(256), 0, stream>>>(
        ei, E, rowp, xoffp, cs4, x, mu, inv_n, W0p, S0, N);
    k_agg_mm<128><<<dim3(nb4), dim3(256), 0, stream>>>(S0, rowp, cs4, dinv, aS0, b0, W1p, S1, N);
    k_agg_mm<40><<<dim3(nb4), dim3(256), 0, stream>>>(S1, rowp, cs4, dinv, aS1, b1, W2p, S2, N);
    k_agg_out<<<dim3(nb4), dim3(256), 0, stream>>>(S2, rowp, cs4, dinv, aS2, b2, out, N);
    (void)out_size; (void)ws_size; (void)n_in;
}

// Round 5
// 458.752 us; speedup vs baseline: 1.4962x; 1.4962x over previous
//
#include <hip/hip_runtime.h>
#include <math.h>

#define IN_DIM 256
#define HD 128
#define OUT_DIM 40
#define S2_STRIDE 64
#define NB_CS 1024  // colsum blocks in fuse1
#define NXCD 8
#define NCHUNK 64   // edge-list chunks (parallelism of sort phases)
#define NRANGE 8    // dst ranges (rescan factor)
#define RMAXW 6400  // u32 words of packed u16 counters: 12800 nodes/range (N <= 102400)

// physical XCD id (0..7), verified on gfx950 via s_getreg(HW_REG_XCC_ID)
__device__ __forceinline__ int xcc_id() {
    int x;
    asm volatile("s_getreg_b32 %0, hwreg(HW_REG_XCC_ID)" : "=s"(x));
    return x & (NXCD - 1);
}

// ---------------- init ----------------
__global__ __launch_bounds__(256) void k_init(float* muacc8) {
    int i = blockIdx.x * 256 + threadIdx.x;
    if (i < NXCD * 256) muacc8[i] = 0.f;
}

// ---------------- fuse1: colsum (float4) + count-sort histogram + wprep ----
// count role: block (r,c) scans edge chunk c (E/64 edges), LDS-histograms dsts
// in range r with packed u16 counters. No global atomics anywhere.
__global__ __launch_bounds__(256) void k_fuse1(const float* __restrict__ x, int N,
                                               float* __restrict__ muacc8,
                                               const int* __restrict__ ei, int E,
                                               unsigned char* __restrict__ cntC,
                                               const float* __restrict__ W0,
                                               const float* __restrict__ W1,
                                               const float* __restrict__ W2,
                                               unsigned long long* W0p,
                                               unsigned long long* W1p,
                                               unsigned long long* W2p,
                                               float* aS0, float* aS1, float* aS2) {
    __shared__ __align__(16) unsigned ldsbuf[RMAXW];
    int b = blockIdx.x, tid = threadIdx.x;
    if (b < NB_CS) {                       // ---- colsum ----
        float* lds = (float*)ldsbuf;
        size_t F4 = (size_t)N * (IN_DIM / 4);
        size_t stride = (size_t)NB_CS * 256;
        float a0 = 0.f, a1 = 0.f, a2 = 0.f, a3 = 0.f;
        const float4* x4 = (const float4*)x;
        for (size_t i = (size_t)b * 256 + tid; i < F4; i += stride) {
            float4 v = x4[i];
            a0 += v.x; a1 += v.y; a2 += v.z; a3 += v.w;
        }
        lds[tid] = 0.f;
        __syncthreads();
        int c0 = (tid * 4) & 255;
        atomicAdd(&lds[c0], a0);
        atomicAdd(&lds[c0 + 1], a1);
        atomicAdd(&lds[c0 + 2], a2);
        atomicAdd(&lds[c0 + 3], a3);
        __syncthreads();
        int xc = xcc_id();
        __hip_atomic_fetch_add(&muacc8[xc * 256 + tid], lds[tid],
                               __ATOMIC_RELAXED, __HIP_MEMORY_SCOPE_WORKGROUP);
    } else if (b < NB_CS + NCHUNK * NRANGE) {  // ---- count histogram ----
        int bid2 = b - NB_CS;
        int c = bid2 >> 3, r = bid2 & (NRANGE - 1);
        for (int i = tid; i < RMAXW; i += 256) ldsbuf[i] = 0u;
        __syncthreads();
        int R = (N + NRANGE - 1) / NRANGE;
        int base = r * R;
        int lim = N - base; if (lim > R) lim = R; if (lim < 0) lim = 0;
        int chunk = ((E + NCHUNK - 1) / NCHUNK + 3) & ~3;
        int eBeg = c * chunk, eEnd = E < eBeg + chunk ? E : eBeg + chunk;
        const int* dptr = ei + E;
        int e = eBeg;
        if ((((unsigned)(E + eBeg)) & 3u) == 0 && eBeg < eEnd) {
            int n4 = (eEnd - eBeg) >> 2;
            const int4* d4 = (const int4*)(dptr + eBeg);
            for (int i = tid; i < n4; i += 256) {
                int4 v = d4[i];
                unsigned r0 = (unsigned)(v.x - base);
                unsigned r1 = (unsigned)(v.y - base);
                unsigned r2 = (unsigned)(v.z - base);
                unsigned r3 = (unsigned)(v.w - base);
                if (r0 < (unsigned)lim) atomicAdd(&ldsbuf[r0 >> 1], 1u << (16 * (r0 & 1)));
                if (r1 < (unsigned)lim) atomicAdd(&ldsbuf[r1 >> 1], 1u << (16 * (r1 & 1)));
                if (r2 < (unsigned)lim) atomicAdd(&ldsbuf[r2 >> 1], 1u << (16 * (r2 & 1)));
                if (r3 < (unsigned)lim) atomicAdd(&ldsbuf[r3 >> 1], 1u << (16 * (r3 & 1)));
            }
            e = eBeg + (n4 << 2);
        }
        for (e += tid; e < eEnd; e += 256) {
            unsigned rel = (unsigned)(dptr[e] - base);
            if (rel < (unsigned)lim) atomicAdd(&ldsbuf[rel >> 1], 1u << (16 * (rel & 1)));
        }
        __syncthreads();
        for (int i = tid; i < lim; i += 256) {
            unsigned cv = (ldsbuf[i >> 1] >> (16 * (i & 1))) & 0xFFFFu;
            cntC[(size_t)c * N + base + i] = (unsigned char)cv;
        }
    } else {                               // ---- wprep ----
        int b2 = b - NB_CS - NCHUNK * NRANGE;
        int lane = tid & 63, w = tid >> 6;
        if (b2 < 32) {                     // W0: [256,128]
            int j = b2 * 4 + w;
            float asum = 0.f;
            unsigned long long words[4];
            #pragma unroll
            for (int q = 0; q < 4; ++q) {
                float v = W0[(size_t)(4 * lane + q) * HD + j];
                asum += fabsf(v);
                words[q] = __ballot(v < 0.f);
            }
            #pragma unroll
            for (int off = 32; off; off >>= 1) asum += __shfl_xor(asum, off);
            if (lane == 0) {
                aS0[j] = 2.f * asum / 256.f;
                #pragma unroll
                for (int q = 0; q < 4; ++q) W0p[j * 4 + q] = words[q];
            }
        } else if (b2 < 64) {              // W1: [128,128]
            int j = (b2 - 32) * 4 + w;
            int fl = lane & 15, kk = lane >> 4;
            float asum = 0.f;
            unsigned long long words[2];
            #pragma unroll
            for (int q = 0; q < 2; ++q) {
                float v = W1[(size_t)(fl * 8 + 4 * q + kk) * HD + j];
                asum += fabsf(v);
                words[q] = __ballot(v < 0.f);
            }
            #pragma unroll
            for (int off = 32; off; off >>= 1) asum += __shfl_xor(asum, off);
            if (lane == 0) {
                aS1[j] = 2.f * asum / 128.f;
                W1p[j * 2 + 0] = words[0];
                W1p[j * 2 + 1] = words[1];
            }
        } else {                           // W2: [128,40]
            int j = (b2 - 64) * 4 + w;
            int fl = lane & 15, kk = lane >> 4;
            if (j < OUT_DIM) {
                float asum = 0.f;
                unsigned long long words[2];
                #pragma unroll
                for (int q = 0; q < 2; ++q) {
                    float v = W2[(size_t)(fl * 8 + 4 * q + kk) * OUT_DIM + j];
                    asum += fabsf(v);
                    words[q] = __ballot(v < 0.f);
                }
                #pragma unroll
                for (int off = 32; off; off >>= 1) asum += __shfl_xor(asum, off);
                if (lane == 0) {
                    aS2[j] = 2.f * asum / 128.f;
                    W2p[j * 2 + 0] = words[0];
                    W2p[j * 2 + 1] = words[1];
                }
            }
        }
    }
}

// ---------------- CSR build (small kernels) ----------------
// k_bp: per-node running prefix over the 64 chunk counts, IN PLACE
// (cntC becomes exclusive chunk offsets); total count (cnt), dinv;
// per-block sums for CSR scan. Max degree assumed < 256 (E/N = 16 avg).
__global__ __launch_bounds__(256) void k_bp(unsigned char* __restrict__ cntC, int N,
                                            int* bp, float* __restrict__ dinv,
                                            int* __restrict__ cnt) {
    __shared__ int sm[256];
    int i = blockIdx.x * 256 + threadIdx.x;
    int c = 0;
    if (i < N) {
        int run = 0;
        #pragma unroll
        for (int h = 0; h < NCHUNK; ++h) {
            unsigned bc = cntC[(size_t)h * N + i];
            cntC[(size_t)h * N + i] = (unsigned char)run;
            run += (int)bc;
        }
        c = run;
        cnt[i] = run;
        dinv[i] = (float)(1.0 / sqrt((double)(run + 1)));   // +1 self loop
    }
    sm[threadIdx.x] = c;
    __syncthreads();
    for (int off = 128; off; off >>= 1) {
        if (threadIdx.x < off) sm[threadIdx.x] += sm[threadIdx.x + off];
        __syncthreads();
    }
    if (threadIdx.x == 0) bp[blockIdx.x] = sm[0];
}

__global__ __launch_bounds__(512) void k_scanbp(const int* __restrict__ bp, int NB, int* bps,
                                                const float* __restrict__ muacc8,
                                                float* __restrict__ mu) {
    __shared__ int sm[512];
    int t = threadIdx.x;
    if (t < 256) {                         // finalize column sums
        float s = 0.f;
        #pragma unroll
        for (int xc = 0; xc < NXCD; ++xc) s += muacc8[xc * 256 + t];
        mu[t] = s;
    }
    int v = (t < NB) ? bp[t] : 0;
    sm[t] = v;
    __syncthreads();
    for (int off = 1; off < 512; off <<= 1) {
        int add = (t >= off) ? sm[t - off] : 0;
        __syncthreads();
        sm[t] += add;
        __syncthreads();
    }
    if (t < NB) bps[t] = sm[t] - v;        // exclusive
}

__global__ __launch_bounds__(256) void k_rowptr(const int* __restrict__ cnt,
                                                const int* __restrict__ bps, int N, int E,
                                                int* row_ptr) {
    __shared__ int wsum[4];
    int t = threadIdx.x, lane = t & 63, w = t >> 6;
    int i = blockIdx.x * 256 + t;
    int c = (i < N) ? cnt[i] : 0;
    int v = c;
    #pragma unroll
    for (int off = 1; off < 64; off <<= 1) {
        int n = __shfl_up(v, off);
        if (lane >= off) v += n;
    }
    if (lane == 63) wsum[w] = v;
    __syncthreads();
    int wo = 0;
    for (int k = 0; k < w; ++k) wo += wsum[k];
    int excl = bps[blockIdx.x] + wo + v - c;
    if (i < N) row_ptr[i] = excl;
    if (blockIdx.x == 0 && t == 0) row_ptr[N] = E;
}

// ---------------- fuse2: counting-sort place + layer-0 matmul ----------------
// place role: block (r,c) rescans chunk c, packed-u16 LDS rank counters for
// range r, writes cs4[rowp[d] + xoff(d,c) + lr] = src. No global atomics.
__global__ __launch_bounds__(256) void k_fuse2(const int* __restrict__ ei, int E,
                                               const int* __restrict__ rowp,
                                               const unsigned char* __restrict__ xoffC,
                                               int* __restrict__ cs4,
                                               const float* __restrict__ x,
                                               const float* __restrict__ muacc, float inv_n,
                                               const unsigned long long* __restrict__ W0p,
                                               unsigned char* __restrict__ S0, int N) {
    __shared__ __align__(16) unsigned sh32[RMAXW];
    int b = blockIdx.x, tid = threadIdx.x;
    if (b < NCHUNK * NRANGE) {             // ---- place ----
        int c = b >> 3, r = b & (NRANGE - 1);
        for (int i = tid; i < RMAXW; i += 256) sh32[i] = 0u;
        __syncthreads();
        int R = (N + NRANGE - 1) / NRANGE;
        int base = r * R;
        int lim = N - base; if (lim > R) lim = R; if (lim < 0) lim = 0;
        int chunk = ((E + NCHUNK - 1) / NCHUNK + 3) & ~3;
        int eBeg = c * chunk, eEnd = E < eBeg + chunk ? E : eBeg + chunk;
        int e = eBeg;
        if (((unsigned)eBeg & 3u) == 0 && (((unsigned)(E + eBeg)) & 3u) == 0 && eBeg < eEnd) {
            int n4 = (eEnd - eBeg) >> 2;
            const int4* s4p = (const int4*)(ei + eBeg);
            const int4* d4p = (const int4*)(ei + E + eBeg);
            for (int i = tid; i < n4; i += 256) {
                int4 sv = s4p[i];
                int4 dv = d4p[i];
                int ss[4] = {sv.x, sv.y, sv.z, sv.w};
                int dd[4] = {dv.x, dv.y, dv.z, dv.w};
                #pragma unroll
                for (int k = 0; k < 4; ++k) {
                    unsigned rel = (unsigned)(dd[k] - base);
                    if (rel < (unsigned)lim) {
                        unsigned old = atomicAdd(&sh32[rel >> 1], 1u << (16 * (rel & 1)));
                        int lr = (int)((old >> (16 * (rel & 1))) & 0xFFFFu);
                        int pos = rowp[dd[k]] +
                                  (int)xoffC[(size_t)c * N + dd[k]] + lr;
                        cs4[pos] = ss[k];
                    }
                }
            }
            e = eBeg + (n4 << 2);
        }
        for (e += tid; e < eEnd; e += 256) {
            int d = ei[E + e];
            unsigned rel = (unsigned)(d - base);
            if (rel < (unsigned)lim) {
                unsigned old = atomicAdd(&sh32[rel >> 1], 1u << (16 * (rel & 1)));
                int lr = (int)((old >> (16 * (rel & 1))) & 0xFFFFu);
                int pos = rowp[d] + (int)xoffC[(size_t)c * N + d] + lr;
                cs4[pos] = ei[e];
            }
        }
    } else {                               // ---- x_mm0 ----
        unsigned long long* w0s = (unsigned long long*)sh32;  // stride-9 layout, 576 words
        {
            int i = tid;
            w0s[9 * (i >> 3) + (i & 7)] = W0p[i];
            i = tid + 256;
            w0s[9 * (i >> 3) + (i & 7)] = W0p[i];
        }
        __syncthreads();
        int lane = tid & 63;
        int row = (b - NCHUNK * NRANGE) * 4 + (tid >> 6);
        if (row >= N) return;
        float4 xv = ((const float4*)(x + (size_t)row * IN_DIM))[lane];
        float4 ms = ((const float4*)muacc)[lane];
        unsigned long long xw[4];
        xw[0] = __ballot(xv.x < ms.x * inv_n);
        xw[1] = __ballot(xv.y < ms.y * inv_n);
        xw[2] = __ballot(xv.z < ms.z * inv_n);
        xw[3] = __ballot(xv.w < ms.w * inv_n);
        unsigned int pack = 0;
        #pragma unroll
        for (int t2 = 0; t2 < 2; ++t2) {
            const unsigned long long* wc = &w0s[9 * lane + 4 * t2];
            int dd = __popcll(xw[0] ^ wc[0]) + __popcll(xw[1] ^ wc[1]) +
                     __popcll(xw[2] ^ wc[2]) + __popcll(xw[3] ^ wc[3]);
            int S = IN_DIM - 2 * dd;   // even, [-256,256]
            int s8 = S >> 1;
            if (s8 > 127) s8 = 127;
            pack |= ((unsigned int)(s8 + 128) & 0xffu) << (8 * t2);
        }
        *(unsigned short*)(S0 + (size_t)row * HD + 2 * lane) = (unsigned short)pack;
    }
}

// byte->float unpack + centering: (v>>8k)&0xff maps to v_cvt_f32_ubyteN
__device__ __forceinline__ void acc4s(float n, unsigned v, float* a) {
    a[0] = fmaf(n, (float)(v & 0xffu) - 128.f, a[0]);
    a[1] = fmaf(n, (float)((v >> 8) & 0xffu) - 128.f, a[1]);
    a[2] = fmaf(n, (float)((v >> 16) & 0xffu) - 128.f, a[2]);
    a[3] = fmaf(n, (float)(v >> 24) - 128.f, a[3]);
}

// ---------------- agg + binarize + fused next popcount matmul ----------------
// wave = 1 dst; 4 slots x 16 lanes; lane loads 8B; edges batched 4 deep.
template <int OUTC>
__global__ __launch_bounds__(256) void k_agg_mm(const unsigned char* __restrict__ Sin, // [N][128]
                                                const int* __restrict__ row_ptr,
                                                const int* __restrict__ cs4,
                                                const float* __restrict__ dinv,
                                                const float* __restrict__ alphaS,
                                                const float* __restrict__ bias,
                                                const unsigned long long* __restrict__ Wnp,
                                                unsigned char* __restrict__ Sout, int N) {
    __shared__ unsigned long long wsm[OUTC * 2 + OUTC / 4 + 8];  // stride-9 swizzled
    int tid = threadIdx.x;
    for (int i = tid; i < OUTC * 2; i += 256) wsm[9 * (i >> 3) + (i & 7)] = Wnp[i];
    __syncthreads();
    int lane = tid & 63;
    int d = blockIdx.x * 4 + (tid >> 6);
    if (d >= N) return;
    int sub = lane >> 4;       // edge slot 0..3
    int fl  = lane & 15;       // 8-byte feature group
    float dv = dinv[d];
    float acc[8];
    #pragma unroll
    for (int k = 0; k < 8; ++k) acc[k] = 0.f;
    if (sub == 0) {            // self loop
        float nrm = dv * dv;
        unsigned long long rr = *(const unsigned long long*)(Sin + (size_t)d * HD + fl * 8);
        acc4s(nrm, (unsigned)rr, acc);
        acc4s(nrm, (unsigned)(rr >> 32), acc + 4);
    }
    int e0 = row_ptr[d], e1 = row_ptr[d + 1];
    int e = e0 + sub;
    for (; e + 12 < e1; e += 16) {         // 4 edges in flight
        int s0_ = cs4[e], s1_ = cs4[e + 4], s2_ = cs4[e + 8], s3_ = cs4[e + 12];
        float n0 = dinv[s0_] * dv, n1 = dinv[s1_] * dv;
        float n2 = dinv[s2_] * dv, n3 = dinv[s3_] * dv;
        unsigned long long r0 = *(const unsigned long long*)(Sin + (size_t)s0_ * HD + fl * 8);
        unsigned long long r1 = *(const unsigned long long*)(Sin + (size_t)s1_ * HD + fl * 8);
        unsigned long long r2 = *(const unsigned long long*)(Sin + (size_t)s2_ * HD + fl * 8);
        unsigned long long r3 = *(const unsigned long long*)(Sin + (size_t)s3_ * HD + fl * 8);
        acc4s(n0, (unsigned)r0, acc); acc4s(n0, (unsigned)(r0 >> 32), acc + 4);
        acc4s(n1, (unsigned)r1, acc); acc4s(n1, (unsigned)(r1 >> 32), acc + 4);
        acc4s(n2, (unsigned)r2, acc); acc4s(n2, (unsigned)(r2 >> 32), acc + 4);
        acc4s(n3, (unsigned)r3, acc); acc4s(n3, (unsigned)(r3 >> 32), acc + 4);
    }
    for (; e + 4 < e1; e += 8) {           // 2 edges
        int sa = cs4[e], sb = cs4[e + 4];
        float na = dinv[sa] * dv, nb = dinv[sb] * dv;
        unsigned long long ra = *(const unsigned long long*)(Sin + (size_t)sa * HD + fl * 8);
        unsigned long long rb = *(const unsigned long long*)(Sin + (size_t)sb * HD + fl * 8);
        acc4s(na, (unsigned)ra, acc); acc4s(na, (unsigned)(ra >> 32), acc + 4);
        acc4s(nb, (unsigned)rb, acc); acc4s(nb, (unsigned)(rb >> 32), acc + 4);
    }
    if (e < e1) {                          // tail
        int s = cs4[e];
        float nrm = dinv[s] * dv;
        unsigned long long rr = *(const unsigned long long*)(Sin + (size_t)s * HD + fl * 8);
        acc4s(nrm, (unsigned)rr, acc);
        acc4s(nrm, (unsigned)(rr >> 32), acc + 4);
    }
    // reduce across the 4 slots (allreduce -> every lane has full acc)
    #pragma unroll
    for (int k = 0; k < 8; ++k) {
        acc[k] += __shfl_xor(acc[k], 16);
        acc[k] += __shfl_xor(acc[k], 32);
    }
    // activation sign bits: feature f = fl*8 + k
    unsigned int m8 = 0;
    #pragma unroll
    for (int k = 0; k < 8; ++k) {
        int f = fl * 8 + k;
        float v = alphaS[f] * acc[k] + bias[f];
        if (v < 0.f) m8 |= (1u << k);
    }
    // assemble 128-bit sign vector: word q=k>>2, bit (fl + 16*(k&3))
    unsigned long long x0 = 0, x1 = 0;
    #pragma unroll
    for (int k = 0; k < 4; ++k) {
        unsigned long long bk = __ballot((m8 >> k) & 1u);
        x0 |= (bk & 0xffffULL) << (16 * k);
    }
    #pragma unroll
    for (int k = 4; k < 8; ++k) {
        unsigned long long bk = __ballot((m8 >> k) & 1u);
        x1 |= (bk & 0xffffULL) << (16 * (k - 4));
    }
    if (OUTC == 128) {
        unsigned int pack = 0;
        #pragma unroll
        for (int t2 = 0; t2 < 2; ++t2) {
            int j = 2 * lane + t2;
            int i0 = j * 2;
            const unsigned long long* wc = &wsm[9 * (i0 >> 3) + (i0 & 7)];
            int dd = __popcll(x0 ^ wc[0]) + __popcll(x1 ^ wc[1]);
            int S = HD - 2 * dd;  // even, [-128,128]
            pack |= ((unsigned int)((S >> 1) + 128) & 0xffu) << (8 * t2);
        }
        *(unsigned short*)(Sout + (size_t)d * HD + 2 * lane) = (unsigned short)pack;
    } else {
        int p8 = 128;  // biased zero padding
        if (lane < OUTC) {
            int i0 = lane * 2;
            const unsigned long long* wc = &wsm[9 * (i0 >> 3) + (i0 & 7)];
            int dd = __popcll(x0 ^ wc[0]) + __popcll(x1 ^ wc[1]);
            p8 = ((HD - 2 * dd) >> 1) + 128;
        }
        Sout[(size_t)d * S2_STRIDE + lane] = (unsigned char)p8;
    }
}

// ---------------- final agg + log_softmax ----------------
__global__ __launch_bounds__(256) void k_agg_out(const unsigned char* __restrict__ S2, // [N][64]
                                                 const int* __restrict__ row_ptr,
                                                 const int* __restrict__ cs4,
                                                 const float* __restrict__ dinv,
                                                 const float* __restrict__ alphaS2,
                                                 const float* __restrict__ b2,
                                                 float* __restrict__ out, int N) {
    int tid = threadIdx.x, lane = tid & 63;
    int d = blockIdx.x * 4 + (tid >> 6);
    if (d >= N) return;
    int sub = lane >> 4;
    int fl  = lane & 15;
    float dv = dinv[d];
    float acc[4] = {0.f, 0.f, 0.f, 0.f};
    if (sub == 0) {            // self loop
        float nrm = dv * dv;
        unsigned int r4 = *(const unsigned int*)(S2 + (size_t)d * S2_STRIDE + fl * 4);
        acc4s(nrm, r4, acc);
    }
    int e0 = row_ptr[d], e1 = row_ptr[d + 1];
    int e = e0 + sub;
    for (; e + 12 < e1; e += 16) {         // 4 edges in flight
        int s0_ = cs4[e], s1_ = cs4[e + 4], s2_ = cs4[e + 8], s3_ = cs4[e + 12];
        float n0 = dinv[s0_] * dv, n1 = dinv[s1_] * dv;
        float n2 = dinv[s2_] * dv, n3 = dinv[s3_] * dv;
        unsigned int r0 = *(const unsigned int*)(S2 + (size_t)s0_ * S2_STRIDE + fl * 4);
        unsigned int r1 = *(const unsigned int*)(S2 + (size_t)s1_ * S2_STRIDE + fl * 4);
        unsigned int r2 = *(const unsigned int*)(S2 + (size_t)s2_ * S2_STRIDE + fl * 4);
        unsigned int r3 = *(const unsigned int*)(S2 + (size_t)s3_ * S2_STRIDE + fl * 4);
        acc4s(n0, r0, acc);
        acc4s(n1, r1, acc);
        acc4s(n2, r2, acc);
        acc4s(n3, r3, acc);
    }
    for (; e + 4 < e1; e += 8) {
        int sa = cs4[e], sb = cs4[e + 4];
        float na = dinv[sa] * dv, nb = dinv[sb] * dv;
        unsigned int ra = *(const unsigned int*)(S2 + (size_t)sa * S2_STRIDE + fl * 4);
        unsigned int rb = *(const unsigned int*)(S2 + (size_t)sb * S2_STRIDE + fl * 4);
        acc4s(na, ra, acc);
        acc4s(nb, rb, acc);
    }
    if (e < e1) {
        int s = cs4[e];
        float nrm = dinv[s] * dv;
        unsigned int r4 = *(const unsigned int*)(S2 + (size_t)s * S2_STRIDE + fl * 4);
        acc4s(nrm, r4, acc);
    }
    #pragma unroll
    for (int k = 0; k < 4; ++k) {
        acc[k] += __shfl_xor(acc[k], 16);
        acc[k] += __shfl_xor(acc[k], 32);
    }
    float h[4];
    float mymax = -INFINITY;
    #pragma unroll
    for (int k = 0; k < 4; ++k) {
        int f = fl * 4 + k;
        h[k] = (f < OUT_DIM) ? (alphaS2[f] * acc[k] + b2[f]) : -INFINITY;
        mymax = fmaxf(mymax, h[k]);
    }
    #pragma unroll
    for (int off = 1; off < 16; off <<= 1) mymax = fmaxf(mymax, __shfl_xor(mymax, off));
    float s4 = 0.f;
    #pragma unroll
    for (int k = 0; k < 4; ++k) {
        if (fl * 4 + k < OUT_DIM) s4 += expf(h[k] - mymax);
    }
    #pragma unroll
    for (int off = 1; off < 16; off <<= 1) s4 += __shfl_xor(s4, off);
    float lse = mymax + logf(s4);
    if (sub == 0 && fl < OUT_DIM / 4) {
        float4 o;
        o.x = h[0] - lse; o.y = h[1] - lse; o.z = h[2] - lse; o.w = h[3] - lse;
        *(float4*)(out + (size_t)d * OUT_DIM + fl * 4) = o;
    }
}

// ---------------- launcher ----------------
extern "C" void kernel_launch(void* const* d_in, const int* in_sizes, int n_in,
                              void* d_out, int out_size, void* d_ws, size_t ws_size,
                              hipStream_t stream) {
    const float* x  = (const float*)d_in[0];
    const int*   ei = (const int*)d_in[1];
    const float* W0 = (const float*)d_in[2];
    const float* b0 = (const float*)d_in[3];
    const float* W1 = (const float*)d_in[4];
    const float* b1 = (const float*)d_in[5];
    const float* W2 = (const float*)d_in[6];
    const float* b2 = (const float*)d_in[7];
    float* out = (float*)d_out;

    int N = in_sizes[0] / IN_DIM;
    int E = in_sizes[1] / 2;

    char* ws = (char*)d_ws;
    size_t off = 0;
    auto alloc = [&](size_t bytes) -> void* {
        off = (off + 255) & ~(size_t)255;
        void* p = (void*)(ws + off);
        off += bytes;
        return p;
    };
    float* mu     = (float*)alloc(256 * 4);
    float* muacc8 = (float*)alloc(NXCD * 256 * 4);
    unsigned char* cntC = (unsigned char*)alloc((size_t)NCHUNK * N);  // counts -> offsets (in place)
    int*   cnt    = (int*)alloc((size_t)N * 4);
    float* dinv   = (float*)alloc((size_t)N * 4);
    int*   rowp   = (int*)alloc(((size_t)N + 1) * 4);
    int*   bp     = (int*)alloc(512 * 4);
    int*   bps    = (int*)alloc(512 * 4);
    int*   cs4    = (int*)alloc((size_t)E * 4);
    unsigned char* S0 = (unsigned char*)alloc((size_t)N * HD);
    unsigned char* S1 = (unsigned char*)alloc((size_t)N * HD);
    unsigned char* S2 = (unsigned char*)alloc((size_t)N * S2_STRIDE);
    unsigned long long* W0p = (unsigned long long*)alloc(128 * 4 * 8);
    unsigned long long* W1p = (unsigned long long*)alloc(128 * 2 * 8);
    unsigned long long* W2p = (unsigned long long*)alloc(40 * 2 * 8);
    float* aS0 = (float*)alloc(128 * 4);
    float* aS1 = (float*)alloc(128 * 4);
    float* aS2 = (float*)alloc(40 * 4);

    int nb256 = (N + 255) / 256;
    float inv_n = 1.0f / (float)N;

    k_init<<<dim3(8), dim3(256), 0, stream>>>(muacc8);
    k_fuse1<<<dim3(NB_CS + NCHUNK * NRANGE + 74), dim3(256), 0, stream>>>(
        x, N, muacc8, ei, E, cntC, W0, W1, W2, W0p, W1p, W2p, aS0, aS1, aS2);
    k_bp<<<dim3(nb256), dim3(256), 0, stream>>>(cntC, N, bp, dinv, cnt);
    k_scanbp<<<dim3(1), dim3(512), 0, stream>>>(bp, nb256, bps, muacc8, mu);
    k_rowptr<<<dim3(nb256), dim3(256), 0, stream>>>(cnt, bps, N, E, rowp);

    int nb4 = (N + 3) / 4;
    k_fuse2<<<dim3(NCHUNK * NRANGE + nb4), dim3(256), 0, stream>>>(
        ei, E, rowp, cntC, cs4, x, mu, inv_n, W0p, S0, N);
    k_agg_mm<128><<<dim3(nb4), dim3(256), 0, stream>>>(S0, rowp, cs4, dinv, aS0, b0, W1p, S1, N);
    k_agg_mm<40><<<dim3(nb4), dim3(256), 0, stream>>>(S1, rowp, cs4, dinv, aS1, b1, W2p, S2, N);
    k_agg_out<<<dim3(nb4), dim3(256), 0, stream>>>(S2, rowp, cs4, dinv, aS2, b2, out, N);
    (void)out_size; (void)ws_size; (void)n_in;
}